// Round 1
// 175.382 us; speedup vs baseline: 1.0276x; 1.0276x over previous
//
#include <hip/hip_runtime.h>
#include <hip/hip_bf16.h>
#include <math.h>
#include <stdint.h>

#define NATOMS 4096
#define HD     128
#define NHEAD  4
#define DHEAD  32
#define FDIM   259
#define BATCH  128
#define H3X    384
#define SPLIT  4

typedef __attribute__((ext_vector_type(8))) short short8;
typedef __attribute__((ext_vector_type(4))) float float4v;
typedef __attribute__((ext_vector_type(16))) float f32x16;

__device__ __forceinline__ ushort f2bf(float f) {
    uint32_t u = __float_as_uint(f);
    return (ushort)((u + 0x7fffu + ((u >> 16) & 1u)) >> 16);
}
__device__ __forceinline__ float b2f(ushort u) {
    return __uint_as_float(((uint32_t)u) << 16);
}
__device__ __forceinline__ f32x16 z16() {
    f32x16 v;
#pragma unroll
    for (int i = 0; i < 16; i++) v[i] = 0.f;
    return v;
}

// ---------------- setup: ONLY the qkvw pack (critical path before k_qkv) -----
// All other packing / cell MLP / bidx moved into k_attn's spare blocks.
__global__ __launch_bounds__(256) void k_setup(const float* __restrict__ qkvw,
                                               ushort* __restrict__ Wqkv) {
    int idx = blockIdx.x * 256 + threadIdx.x;   // grid 192 -> idx < 49152
    int k = idx / 384, n = idx - k * 384;
    Wqkv[n * 128 + k] = f2bf(qkvw[idx]);
}

// ---------------- QKV: fused embed+LN prologue, MFMA GEMM, packed outputs -----
// 512 blocks: (row-group, col-half). 2 blocks/CU -> 2 waves/SIMD for latency
// hiding (was 1 wave/SIMD at 256 blocks).
__global__ __launch_bounds__(256) void k_qkv(const int* __restrict__ elems,
                                             const float* __restrict__ emb,
                                             const float* __restrict__ lg,
                                             const float* __restrict__ lb,
                                             const ushort* __restrict__ Wt,
                                             const float* __restrict__ bias,
                                             ushort* __restrict__ Qb, ushort* __restrict__ Kb,
                                             ushort* __restrict__ VTb2) {
    __shared__ alignas(16) ushort Af[4][64][8];
    __shared__ alignas(16) ushort vt[128][16];
    const int t = threadIdx.x, w = t >> 6, lane = t & 63, quad = lane >> 4, lq = lane & 15;
    const int rg = blockIdx.x >> 1, half = blockIdx.x & 1;
    const int rb = rg * 16;
    {
        int row = t >> 4, seg = t & 15;
        int e = elems[rb + row];
        const float* ep = emb + (size_t)e * HD + seg * 8;
        float v[8]; float s = 0.f, ss = 0.f;
#pragma unroll
        for (int j = 0; j < 8; j++) { v[j] = ep[j]; s += v[j]; ss += v[j] * v[j]; }
#pragma unroll
        for (int m = 1; m < 16; m <<= 1) { s += __shfl_xor(s, m); ss += __shfl_xor(ss, m); }
        float mean = s * (1.f / HD);
        float inv = rsqrtf(ss * (1.f / HD) - mean * mean + 1e-5f);
        ushort o[8];
#pragma unroll
        for (int j = 0; j < 8; j++)
            o[j] = f2bf((v[j] - mean) * inv * lg[seg * 8 + j] + lb[seg * 8 + j]);
        *(uint4*)&Af[seg >> 2][(seg & 3) * 16 + row][0] = *(uint4*)o;
    }
    __syncthreads();
    float4v acc[3];
#pragma unroll
    for (int i = 0; i < 3; i++) acc[i] = (float4v){0.f, 0.f, 0.f, 0.f};
#pragma unroll
    for (int kt = 0; kt < 4; kt++) {
        short8 af = *(const short8*)&Af[kt][lane][0];
#pragma unroll
        for (int i = 0; i < 3; i++) {
            int nt = half * 12 + w * 3 + i;
            short8 wf = *(const short8*)(Wt + (size_t)(lq + 16 * nt) * HD + kt * 32 + quad * 8);
            acc[i] = __builtin_amdgcn_mfma_f32_16x16x32_bf16(af, wf, acc[i], 0, 0, 0);
        }
    }
#pragma unroll
    for (int i = 0; i < 3; i++) {
        int col = lq + 16 * (half * 12 + w * 3 + i);
        float bb = bias[col];
#pragma unroll
        for (int r = 0; r < 4; r++) {
            float c = acc[i][r] + bb;
            int rowin = quad * 4 + r;
            int row = rb + rowin;
            if (col < 128) {
                Qb[(size_t)(((col >> 5) * NATOMS) + row) * 32 + (col & 31)] = f2bf(c * 0.25503483f);
            } else if (col < 256) {
                int cc = col - 128;
                Kb[(size_t)(((cc >> 5) * NATOMS) + row) * 32 + (cc & 31)] = f2bf(c);
            } else {
                vt[col - 256][rowin] = f2bf(c);
            }
        }
    }
    __syncthreads();
    if (half == 1 && t < 128) {
        int hh = t >> 5, d = t & 31;
        uint4 a0 = *(const uint4*)&vt[t][0];
        uint4 a1 = *(const uint4*)&vt[t][8];
        ushort* dst = VTb2 + ((size_t)(hh * 64 + (rb >> 6)) * 32 + d) * 64 + (rb & 63);
        *(uint4*)(dst) = a0;
        *(uint4*)(dst + 8) = a1;
    }
}

// ---------------- attention: 32x32x16, S^T/O^T, split-K ----------------------
// grid z extended by 1: the z==SPLIT slab (256 light blocks) does the k_back
// weight packs + cell MLP + bidx/cmin/cmax, riding in attn's occupancy slack.
__global__ __launch_bounds__(256) void k_attn(const ushort* __restrict__ Qb,
                                              const ushort* __restrict__ Kb,
                                              const ushort* __restrict__ VTb2,
                                              ushort* __restrict__ Opart,
                                              float* __restrict__ lpart,
                                              const int* __restrict__ num_atoms,
                                              const float* __restrict__ cell,
                                              const float* __restrict__ aow,
                                              const float* __restrict__ op1w,
                                              const float* __restrict__ r1w,
                                              const float* __restrict__ r2w,
                                              const float* __restrict__ ce_w1,
                                              const float* __restrict__ ce_b1,
                                              const float* __restrict__ ce_w2,
                                              const float* __restrict__ ce_b2,
                                              int* __restrict__ bidx,
                                              float* __restrict__ cmin,
                                              float* __restrict__ cmax,
                                              ushort* __restrict__ Wao,
                                              ushort* __restrict__ Wop1,
                                              ushort* __restrict__ Wr1,
                                              ushort* __restrict__ Wr2,
                                              float* __restrict__ CF) {
    __shared__ alignas(16) ushort P_s[4][32 * 72];
    __shared__ alignas(16) float OL[2][32 * 36];
    __shared__ float LL[2][32];
    const int t = threadIdx.x;

    if (blockIdx.z == SPLIT) {
        // ---- misc slab: packs for k_back (consumed next kernel) ----
        float* hs = (float*)&P_s[0][0];          // 512 B scratch, no overlap w/ start
        int* start = (int*)&P_s[1][0];
        const int mid = blockIdx.y * 64 + blockIdx.x;   // [0,256)
        for (int j = mid * 256 + t; j < 86016; j += 65536) {
            if (j < 16384) {                     // aow [128][128]
                int k = j >> 7, n = j & 127;
                Wao[n * 128 + k] = f2bf(aow[j]);
            } else if (j < 49536) {              // op1w [259][128]
                int jj = j - 16384; int k = jj >> 7, n = jj & 127;
                Wop1[n * 288 + k] = f2bf(op1w[jj]);
            } else if (j < 53248) {              // zero-pad k in [259,288)
                int jj = j - 49536; int n = jj & 127, k = 259 + (jj >> 7);
                Wop1[n * 288 + k] = 0;
            } else if (j < 69632) {              // r1w [128][128]
                int jj = j - 53248; int k = jj >> 7, n = jj & 127;
                Wr1[n * 128 + k] = f2bf(r1w[jj]);
            } else {                             // r2w [128][128]
                int jj = j - 69632; int k = jj >> 7, n = jj & 127;
                Wr2[n * 128 + k] = f2bf(r2w[jj]);
            }
        }
        if (mid < 128) {
            // cell-encoder MLP row `mid`
            if (t < 128) {
                float c0 = cell[mid * 3 + 0], c1 = cell[mid * 3 + 1], c2 = cell[mid * 3 + 2];
                float h = c0 * ce_w1[t] + c1 * ce_w1[HD + t] + c2 * ce_w1[2 * HD + t] + ce_b1[t];
                h = h / (1.f + __expf(-h));
                hs[t] = h;
            }
            __syncthreads();
            if (t < 128) {
                float acc = ce_b2[t];
#pragma unroll 8
                for (int k = 0; k < HD; k++) acc += hs[k] * ce_w2[k * HD + t];
                CF[mid * HD + t] = acc;
            }
        } else if (mid == 128) {
            if (t == 0) {
                int pos = 0;
                for (int b = 0; b < BATCH; b++) { start[b] = pos; pos += num_atoms[b]; }
                start[BATCH] = pos;
            }
            __syncthreads();
            if (t < 128) {
                int s = min(start[t], NATOMS), e = min(start[t + 1], NATOMS);
                for (int j = s; j < e; j++) bidx[j] = t;
                if (t == 0) {
                    int total = min(start[BATCH], NATOMS);
                    for (int j = total; j < NATOMS; j++) bidx[j] = BATCH - 1;
                }
            }
            for (int rr = t; rr < BATCH * 3; rr += 256) {
                float a0 = cell[rr * 3 + 0], a1 = cell[rr * 3 + 1], a2 = cell[rr * 3 + 2];
                cmin[rr] = fminf(a0, fminf(a1, a2)) + 1e-6f;
                cmax[rr] = fmaxf(a0, fmaxf(a1, a2)) - 1e-6f;
            }
        }
        return;
    }

    const int w = t >> 6, lane = t & 63;
    const int l31 = lane & 31, hi = lane >> 5;
    const int qt = w & 1, kh2 = w >> 1;
    const int h = blockIdx.y, sp = blockIdx.z;
    const int q0 = blockIdx.x * 64;
    const int qrow = q0 + qt * 32 + l31;

    short8 qf0 = *(const short8*)(Qb + (size_t)(h * NATOMS + qrow) * 32 + hi * 8);
    short8 qf1 = *(const short8*)(Qb + (size_t)(h * NATOMS + qrow) * 32 + 16 + hi * 8);
    f32x16 O = z16();
    float lp = 0.f;
    ushort* Pw = &P_s[w][0];
    const int kstart = sp * (NATOMS / SPLIT) + kh2 * 64;

    for (int ck = 0; ck < (NATOMS / SPLIT) / 128; ck++) {
        int kb = kstart + ck * 128;
        const ushort* vbase = VTb2 + ((size_t)(h * 64 + (kb >> 6)) * 32 + l31) * 64;
#pragma unroll
        for (int kt = 0; kt < 2; kt++) {
            int kk = kb + kt * 32;
            const ushort* kp = Kb + (size_t)(h * NATOMS + kk + l31) * 32 + hi * 8;
            short8 kf0 = *(const short8*)(kp);
            short8 kf1 = *(const short8*)(kp + 16);
            f32x16 S = z16();
            S = __builtin_amdgcn_mfma_f32_32x32x16_bf16(kf0, qf0, S, 0, 0, 0);
            S = __builtin_amdgcn_mfma_f32_32x32x16_bf16(kf1, qf1, S, 0, 0, 0);
#pragma unroll
            for (int c = 0; c < 4; c++) {
                float p0 = exp2f(S[4 * c + 0]);
                float p1 = exp2f(S[4 * c + 1]);
                float p2 = exp2f(S[4 * c + 2]);
                float p3 = exp2f(S[4 * c + 3]);
                lp += (p0 + p1) + (p2 + p3);
                uint2 u;
                asm("v_cvt_pk_bf16_f32 %0, %1, %2" : "=v"(u.x) : "v"(p0), "v"(p1));
                asm("v_cvt_pk_bf16_f32 %0, %1, %2" : "=v"(u.y) : "v"(p2), "v"(p3));
                *(uint2*)(&Pw[l31 * 72 + kt * 32 + c * 8 + hi * 4]) = u;
            }
#pragma unroll
            for (int wd = 0; wd < 2; wd++) {
                int koff = kt * 32 + wd * 16;
                short8 vf = *(const short8*)(vbase + koff + hi * 8);
                short8 pf = *(const short8*)(&Pw[l31 * 72 + koff + hi * 8]);
                O = __builtin_amdgcn_mfma_f32_32x32x16_bf16(vf, pf, O, 0, 0, 0);
            }
        }
    }
    lp += __shfl_xor(lp, 32);
    if (kh2 == 0) {
#pragma unroll
        for (int c = 0; c < 4; c++) {
            float4 f = {O[4 * c + 0], O[4 * c + 1], O[4 * c + 2], O[4 * c + 3]};
            *(float4*)(&OL[qt][l31 * 36 + c * 8 + hi * 4]) = f;
        }
        if (hi == 0) LL[qt][l31] = lp;
    }
    __syncthreads();
    if (kh2 == 1) {
        lp += LL[qt][l31];
#pragma unroll
        for (int c = 0; c < 4; c++) {
            float4 f = *(const float4*)(&OL[qt][l31 * 36 + c * 8 + hi * 4]);
            float o0 = O[4 * c + 0] + f.x, o1 = O[4 * c + 1] + f.y;
            float o2 = O[4 * c + 2] + f.z, o3 = O[4 * c + 3] + f.w;
            uint2 u;
            u.x = (uint32_t)f2bf(o0) | ((uint32_t)f2bf(o1) << 16);
            u.y = (uint32_t)f2bf(o2) | ((uint32_t)f2bf(o3) << 16);
            *(uint2*)(Opart + (size_t)(sp * NATOMS + qrow) * HD + h * 32 + c * 8 + hi * 4) = u;
        }
        if (hi == 0) lpart[sp * (NHEAD * NATOMS) + h * NATOMS + qrow] = lp;
    }
}

// ---------------- back: fused ao+comb+op1+r1+r2+LN+w3+clamp, 8 waves ----------
__global__ __launch_bounds__(512) void k_back(
        const ushort* __restrict__ Opart, const float* __restrict__ lpart,
        const ushort* __restrict__ Wao, const float* __restrict__ aob,
        const float* __restrict__ CF, const float* __restrict__ coord,
        const int* __restrict__ bidx,
        const float* __restrict__ fg, const float* __restrict__ fb,
        const ushort* __restrict__ Wop1, const float* __restrict__ op1b,
        const float* __restrict__ l1g, const float* __restrict__ l1b,
        const ushort* __restrict__ Wr1, const float* __restrict__ r1b,
        const float* __restrict__ rlg, const float* __restrict__ rlb,
        const ushort* __restrict__ Wr2, const float* __restrict__ r2b,
        const float* __restrict__ l2g, const float* __restrict__ l2b,
        const float* __restrict__ w3, const float* __restrict__ b3,
        const float* __restrict__ cmin, const float* __restrict__ cmax,
        float* __restrict__ out) {
    __shared__ alignas(16) ushort AF1[9][64][8];
    __shared__ alignas(16) ushort AF2[4][64][8];
    __shared__ alignas(16) ushort AF3[4][64][8];
    __shared__ float RED[8][16][4];
    __shared__ float REDC[16][2];
    __shared__ float COORDS[16][3];
    const int t = threadIdx.x, w = t >> 6, lane = t & 63, quad = lane >> 4, lq = lane & 15;
    const int rb = blockIdx.x * 16;
    const int col = lq + 16 * w;

    // ---- stage A: split-combine + attn-out GEMM ----
    const int arow = rb + lq;
    float4v a0 = {0.f, 0.f, 0.f, 0.f};
#pragma unroll
    for (int h = 0; h < 4; h++) {
        float l = 0.f;
#pragma unroll
        for (int s = 0; s < SPLIT; s++) l += lpart[s * (NHEAD * NATOMS) + h * NATOMS + arow];
        float inv = 1.f / l;
        float pv[8];
#pragma unroll
        for (int j = 0; j < 8; j++) pv[j] = 0.f;
#pragma unroll
        for (int s = 0; s < SPLIT; s++) {
            short8 ov = *(const short8*)(Opart + (size_t)(s * NATOMS + arow) * HD + h * 32 + quad * 8);
#pragma unroll
            for (int j = 0; j < 8; j++) pv[j] += b2f((ushort)ov[j]);
        }
        short8 af;
#pragma unroll
        for (int j = 0; j < 8; j++) af[j] = (short)f2bf(pv[j] * inv);
        short8 w0 = *(const short8*)(Wao + (size_t)col * HD + h * 32 + quad * 8);
        a0 = __builtin_amdgcn_mfma_f32_16x16x32_bf16(af, w0, a0, 0, 0, 0);
    }
    float x1[4];
#pragma unroll
    for (int r = 0; r < 4; r++) x1[r] = a0[r] + aob[col];

    // ---- stage B: comb LN(259) -> AF1 ----
    float cfv[4];
#pragma unroll
    for (int r = 0; r < 4; r++) cfv[r] = CF[bidx[rb + quad * 4 + r] * HD + col];
#pragma unroll
    for (int r = 0; r < 4; r++) {
        float s1 = x1[r] + cfv[r];
        float s2 = x1[r] * x1[r] + cfv[r] * cfv[r];
#pragma unroll
        for (int m = 1; m < 16; m <<= 1) { s1 += __shfl_xor(s1, m); s2 += __shfl_xor(s2, m); }
        if (lq == 0) { RED[w][quad * 4 + r][0] = s1; RED[w][quad * 4 + r][1] = s2; }
    }
    if (t < 16) {
        float c0 = coord[(rb + t) * 3 + 0], c1 = coord[(rb + t) * 3 + 1], c2 = coord[(rb + t) * 3 + 2];
        COORDS[t][0] = c0; COORDS[t][1] = c1; COORDS[t][2] = c2;
        REDC[t][0] = c0 + c1 + c2; REDC[t][1] = c0 * c0 + c1 * c1 + c2 * c2;
    }
    if (t < 64) { uint4 z = {0, 0, 0, 0}; *(uint4*)&AF1[8][t][0] = z; }
    __syncthreads();
#pragma unroll
    for (int r = 0; r < 4; r++) {
        int ri = quad * 4 + r;
        float s1 = REDC[ri][0], s2 = REDC[ri][1];
#pragma unroll
        for (int ww = 0; ww < 8; ww++) { s1 += RED[ww][ri][0]; s2 += RED[ww][ri][1]; }
        float mn = s1 * (1.f / FDIM);
        float iv = rsqrtf(s2 * (1.f / FDIM) - mn * mn + 1e-5f);
        float vx = (x1[r] - mn) * iv * fg[col] + fb[col];
        float vc = (cfv[r] - mn) * iv * fg[col + 128] + fb[col + 128];
        AF1[col >> 5][((col >> 3) & 3) * 16 + ri][col & 7] = f2bf(vx);
        int c2 = col + 128;
        AF1[c2 >> 5][((c2 >> 3) & 3) * 16 + ri][c2 & 7] = f2bf(vc);
    }
    if (t < 16) {
        float s1 = REDC[t][0], s2 = REDC[t][1];
#pragma unroll
        for (int ww = 0; ww < 8; ww++) { s1 += RED[ww][t][0]; s2 += RED[ww][t][1]; }
        float mn = s1 * (1.f / FDIM);
        float iv = rsqrtf(s2 * (1.f / FDIM) - mn * mn + 1e-5f);
#pragma unroll
        for (int c = 0; c < 3; c++)
            AF1[8][t][c] = f2bf((COORDS[t][c] - mn) * iv * fg[256 + c] + fb[256 + c]);
    }
    __syncthreads();

    // ---- stage C: op1 (K=288) + LN + silu -> AF2 ----
    float4v cv = {0.f, 0.f, 0.f, 0.f};
#pragma unroll
    for (int kt = 0; kt < 9; kt++) {
        short8 af = *(const short8*)&AF1[kt][lane][0];
        short8 w0 = *(const short8*)(Wop1 + (size_t)col * 288 + kt * 32 + quad * 8);
        cv = __builtin_amdgcn_mfma_f32_16x16x32_bf16(af, w0, cv, 0, 0, 0);
    }
    float h0[4];
#pragma unroll
    for (int r = 0; r < 4; r++) {
        h0[r] = cv[r] + op1b[col];
        float s1 = h0[r], s2 = h0[r] * h0[r];
#pragma unroll
        for (int m = 1; m < 16; m <<= 1) { s1 += __shfl_xor(s1, m); s2 += __shfl_xor(s2, m); }
        if (lq == 0) { RED[w][quad * 4 + r][0] = s1; RED[w][quad * 4 + r][1] = s2; }
    }
    __syncthreads();
#pragma unroll
    for (int r = 0; r < 4; r++) {
        int ri = quad * 4 + r;
        float s1 = 0.f, s2 = 0.f;
#pragma unroll
        for (int ww = 0; ww < 8; ww++) { s1 += RED[ww][ri][0]; s2 += RED[ww][ri][1]; }
        float mn = s1 * (1.f / HD);
        float iv = rsqrtf(s2 * (1.f / HD) - mn * mn + 1e-5f);
        float o = (h0[r] - mn) * iv * l1g[col] + l1b[col];
        o = o / (1.f + __expf(-o));
        AF2[col >> 5][((col >> 3) & 3) * 16 + ri][col & 7] = f2bf(o);
    }
    __syncthreads();

    // ---- stage D: r1 + LN + silu -> AF3 ----
    float4v dv = {0.f, 0.f, 0.f, 0.f};
#pragma unroll
    for (int kt = 0; kt < 4; kt++) {
        short8 af = *(const short8*)&AF2[kt][lane][0];
        short8 w0 = *(const short8*)(Wr1 + (size_t)col * HD + kt * 32 + quad * 8);
        dv = __builtin_amdgcn_mfma_f32_16x16x32_bf16(af, w0, dv, 0, 0, 0);
    }
    float e0[4];
#pragma unroll
    for (int r = 0; r < 4; r++) {
        e0[r] = dv[r] + r1b[col];
        float s1 = e0[r], s2 = e0[r] * e0[r];
#pragma unroll
        for (int m = 1; m < 16; m <<= 1) { s1 += __shfl_xor(s1, m); s2 += __shfl_xor(s2, m); }
        if (lq == 0) { RED[w][quad * 4 + r][0] = s1; RED[w][quad * 4 + r][1] = s2; }
    }
    __syncthreads();
#pragma unroll
    for (int r = 0; r < 4; r++) {
        int ri = quad * 4 + r;
        float s1 = 0.f, s2 = 0.f;
#pragma unroll
        for (int ww = 0; ww < 8; ww++) { s1 += RED[ww][ri][0]; s2 += RED[ww][ri][1]; }
        float mn = s1 * (1.f / HD);
        float iv = rsqrtf(s2 * (1.f / HD) - mn * mn + 1e-5f);
        float o = (e0[r] - mn) * iv * rlg[col] + rlb[col];
        o = o / (1.f + __expf(-o));
        AF3[col >> 5][((col >> 3) & 3) * 16 + ri][col & 7] = f2bf(o);
    }
    __syncthreads();

    // ---- stage E: r2 + resid + LN + w3 + tanh + clamp ----
    float4v fv = {0.f, 0.f, 0.f, 0.f};
#pragma unroll
    for (int kt = 0; kt < 4; kt++) {
        short8 af = *(const short8*)&AF3[kt][lane][0];
        short8 w0 = *(const short8*)(Wr2 + (size_t)col * HD + kt * 32 + quad * 8);
        fv = __builtin_amdgcn_mfma_f32_16x16x32_bf16(af, w0, fv, 0, 0, 0);
    }
    float g0r[4];
#pragma unroll
    for (int r = 0; r < 4; r++) {
        int ri = quad * 4 + r;
        float rs = b2f(AF2[col >> 5][((col >> 3) & 3) * 16 + ri][col & 7]);
        g0r[r] = fv[r] + r2b[col] + rs;
        float s1 = g0r[r], s2 = g0r[r] * g0r[r];
#pragma unroll
        for (int m = 1; m < 16; m <<= 1) { s1 += __shfl_xor(s1, m); s2 += __shfl_xor(s2, m); }
        if (lq == 0) { RED[w][ri][0] = s1; RED[w][ri][1] = s2; }
    }
    __syncthreads();
    float tp[4][3];
#pragma unroll
    for (int r = 0; r < 4; r++) {
        int ri = quad * 4 + r;
        float s1 = 0.f, s2 = 0.f;
#pragma unroll
        for (int ww = 0; ww < 8; ww++) { s1 += RED[ww][ri][0]; s2 += RED[ww][ri][1]; }
        float mn = s1 * (1.f / HD);
        float iv = rsqrtf(s2 * (1.f / HD) - mn * mn + 1e-5f);
        float h2 = (g0r[r] - mn) * iv * l2g[col] + l2b[col];
#pragma unroll
        for (int c = 0; c < 3; c++) {
            float v = h2 * w3[col * 3 + c];
#pragma unroll
            for (int m = 1; m < 16; m <<= 1) v += __shfl_xor(v, m);
            tp[r][c] = v;
        }
    }
    __syncthreads();
    if (lq == 0) {
#pragma unroll
        for (int r = 0; r < 4; r++) {
            RED[w][quad * 4 + r][0] = tp[r][0];
            RED[w][quad * 4 + r][1] = tp[r][1];
            RED[w][quad * 4 + r][2] = tp[r][2];
        }
    }
    __syncthreads();
    if (t < 16) {
        int bi = bidx[rb + t];
#pragma unroll
        for (int c = 0; c < 3; c++) {
            float sv = 0.f;
#pragma unroll
            for (int ww = 0; ww < 8; ww++) sv += RED[ww][t][c];
            float off = tanhf(sv + b3[c]) * 0.01f;
            float pert = COORDS[t][c] + off;
            pert = fminf(fmaxf(pert, cmin[bi * 3 + c]), cmax[bi * 3 + c]);
            out[(rb + t) * 3 + c] = pert;
        }
    }
}

extern "C" void kernel_launch(void* const* d_in, const int* in_sizes, int n_in,
                              void* d_out, int out_size, void* d_ws, size_t ws_size,
                              hipStream_t stream) {
    const int* num_atoms = (const int*)d_in[0];
    const int* elems = (const int*)d_in[1];
    const float* cell = (const float*)d_in[2];
    const float* coord = (const float*)d_in[3];
    const float* emb = (const float*)d_in[4];
    const float* ln_in_g = (const float*)d_in[5];
    const float* ln_in_b = (const float*)d_in[6];
    const float* attn_in_w = (const float*)d_in[7];
    const float* attn_in_b = (const float*)d_in[8];
    const float* attn_out_w = (const float*)d_in[9];
    const float* attn_out_b = (const float*)d_in[10];
    const float* ce_w1 = (const float*)d_in[11];
    const float* ce_b1 = (const float*)d_in[12];
    const float* ce_w2 = (const float*)d_in[13];
    const float* ce_b2 = (const float*)d_in[14];
    const float* ln_feat_g = (const float*)d_in[15];
    const float* ln_feat_b = (const float*)d_in[16];
    const float* op_w1 = (const float*)d_in[17];
    const float* op_b1 = (const float*)d_in[18];
    const float* op_ln1_g = (const float*)d_in[19];
    const float* op_ln1_b = (const float*)d_in[20];
    const float* res_w1 = (const float*)d_in[21];
    const float* res_b1 = (const float*)d_in[22];
    const float* res_ln_g = (const float*)d_in[23];
    const float* res_ln_b = (const float*)d_in[24];
    const float* res_w2 = (const float*)d_in[25];
    const float* res_b2 = (const float*)d_in[26];
    const float* op_ln2_g = (const float*)d_in[27];
    const float* op_ln2_b = (const float*)d_in[28];
    const float* op_w3 = (const float*)d_in[29];
    const float* op_b3 = (const float*)d_in[30];

    char* ws = (char*)d_ws;
    const size_t MB = 1u << 20;
    ushort* Qb = (ushort*)(ws);
    ushort* Kb = (ushort*)(ws + 1 * MB);
    ushort* VTb2 = (ushort*)(ws + 2 * MB);
    ushort* Opart = (ushort*)(ws + 3 * MB);
    float* lpart = (float*)(ws + 7 * MB);
    int* bidx = (int*)(ws + 7 * MB + (256u << 10));
    float* cmin = (float*)(ws + 7 * MB + (272u << 10));
    float* cmax = (float*)(ws + 7 * MB + (274u << 10));
    float* CF = (float*)(ws + 7 * MB + (276u << 10));
    ushort* Wqkv = (ushort*)(ws + 7 * MB + (340u << 10));
    ushort* Wao = (ushort*)(ws + 7 * MB + (436u << 10));
    ushort* Wop1 = (ushort*)(ws + 7 * MB + (468u << 10));
    ushort* Wr1 = (ushort*)(ws + 7 * MB + (540u << 10));
    ushort* Wr2 = (ushort*)(ws + 7 * MB + (572u << 10));

    k_setup<<<192, 256, 0, stream>>>(attn_in_w, Wqkv);
    k_qkv<<<512, 256, 0, stream>>>(elems, emb, ln_in_g, ln_in_b, Wqkv, attn_in_b,
                                   Qb, Kb, VTb2);
    k_attn<<<dim3(NATOMS / 64, NHEAD, SPLIT + 1), 256, 0, stream>>>(
        Qb, Kb, VTb2, Opart, lpart,
        num_atoms, cell, attn_out_w, op_w1, res_w1, res_w2,
        ce_w1, ce_b1, ce_w2, ce_b2, bidx, cmin, cmax,
        Wao, Wop1, Wr1, Wr2, CF);
    k_back<<<256, 512, 0, stream>>>(Opart, lpart, Wao, attn_out_b, CF, coord, bidx,
                                    ln_feat_g, ln_feat_b, Wop1, op_b1, op_ln1_g, op_ln1_b,
                                    Wr1, res_b1, res_ln_g, res_ln_b, Wr2, res_b2,
                                    op_ln2_g, op_ln2_b, op_w3, op_b3, cmin, cmax,
                                    (float*)d_out);
}

// Round 2
// 169.860 us; speedup vs baseline: 1.0610x; 1.0325x over previous
//
#include <hip/hip_runtime.h>
#include <hip/hip_bf16.h>
#include <math.h>
#include <stdint.h>

#define NATOMS 4096
#define HD     128
#define NHEAD  4
#define DHEAD  32
#define FDIM   259
#define BATCH  128
#define H3X    384
#define SPLIT  4

typedef __attribute__((ext_vector_type(8))) short short8;
typedef __attribute__((ext_vector_type(4))) float float4v;
typedef __attribute__((ext_vector_type(16))) float f32x16;

__device__ __forceinline__ ushort f2bf(float f) {
    uint32_t u = __float_as_uint(f);
    return (ushort)((u + 0x7fffu + ((u >> 16) & 1u)) >> 16);
}
__device__ __forceinline__ float b2f(ushort u) {
    return __uint_as_float(((uint32_t)u) << 16);
}
__device__ __forceinline__ f32x16 z16() {
    f32x16 v;
#pragma unroll
    for (int i = 0; i < 16; i++) v[i] = 0.f;
    return v;
}

// ---------------- QKV: per-block in-LDS weight pack + embed+LN + MFMA GEMM ----
// k_setup is GONE: each block packs its own 192-col slice of attn_in_w into
// LDS in fragment-linear order (conflict-free b128 write/read), overlapped
// with the embed+LN prologue under the one existing barrier. 4 -> 3 dispatches.
__global__ __launch_bounds__(256) void k_qkv(const int* __restrict__ elems,
                                             const float* __restrict__ emb,
                                             const float* __restrict__ lg,
                                             const float* __restrict__ lb,
                                             const float* __restrict__ qkvw,
                                             const float* __restrict__ bias,
                                             ushort* __restrict__ Qb, ushort* __restrict__ Kb,
                                             ushort* __restrict__ VTb2) {
    __shared__ alignas(16) ushort Wl[48 * 512];   // 48 KB: 48 chunks x 64 lanes x 8 bf16
    __shared__ alignas(16) ushort Af[4][64][8];
    __shared__ alignas(16) ushort vt[128][16];
    const int t = threadIdx.x, w = t >> 6, lane = t & 63, quad = lane >> 4, lq = lane & 15;
    const int rg = blockIdx.x >> 1, half = blockIdx.x & 1;
    const int rb = rg * 16;

    // ---- weight pack: this block's half (cols [half*192, half*192+192)) ----
    // slot s = t + 256*m; chunk = s>>6 (const per wave-instr), lane-linear 16B writes.
#pragma unroll
    for (int m = 0; m < 12; m++) {
        int s = t + 256 * m;
        int chunk = s >> 6, l = s & 63;
        int ntl = chunk >> 2, kt = chunk & 3;
        int q8 = (l >> 4) * 8, lqq = l & 15;
        int n = half * 192 + ntl * 16 + lqq;
        int k0 = kt * 32 + q8;
        ushort o[8];
#pragma unroll
        for (int j = 0; j < 8; j++) o[j] = f2bf(qkvw[(k0 + j) * H3X + n]);
        *(uint4*)&Wl[(chunk << 9) + (l << 3)] = *(uint4*)o;
    }

    // ---- embed + LN prologue ----
    {
        int row = t >> 4, seg = t & 15;
        int e = elems[rb + row];
        const float* ep = emb + (size_t)e * HD + seg * 8;
        float v[8]; float s = 0.f, ss = 0.f;
#pragma unroll
        for (int j = 0; j < 8; j++) { v[j] = ep[j]; s += v[j]; ss += v[j] * v[j]; }
#pragma unroll
        for (int m = 1; m < 16; m <<= 1) { s += __shfl_xor(s, m); ss += __shfl_xor(ss, m); }
        float mean = s * (1.f / HD);
        float inv = rsqrtf(ss * (1.f / HD) - mean * mean + 1e-5f);
        ushort o[8];
#pragma unroll
        for (int j = 0; j < 8; j++)
            o[j] = f2bf((v[j] - mean) * inv * lg[seg * 8 + j] + lb[seg * 8 + j]);
        *(uint4*)&Af[seg >> 2][(seg & 3) * 16 + row][0] = *(uint4*)o;
    }
    __syncthreads();

    float4v acc[3];
#pragma unroll
    for (int i = 0; i < 3; i++) acc[i] = (float4v){0.f, 0.f, 0.f, 0.f};
#pragma unroll
    for (int kt = 0; kt < 4; kt++) {
        short8 af = *(const short8*)&Af[kt][lane][0];
#pragma unroll
        for (int i = 0; i < 3; i++) {
            short8 wf = *(const short8*)&Wl[((((w * 3 + i) << 2) + kt) << 9) + (lane << 3)];
            acc[i] = __builtin_amdgcn_mfma_f32_16x16x32_bf16(af, wf, acc[i], 0, 0, 0);
        }
    }
#pragma unroll
    for (int i = 0; i < 3; i++) {
        int col = lq + 16 * (half * 12 + w * 3 + i);
        float bb = bias[col];
#pragma unroll
        for (int r = 0; r < 4; r++) {
            float c = acc[i][r] + bb;
            int rowin = quad * 4 + r;
            int row = rb + rowin;
            if (col < 128) {
                Qb[(size_t)(((col >> 5) * NATOMS) + row) * 32 + (col & 31)] = f2bf(c * 0.25503483f);
            } else if (col < 256) {
                int cc = col - 128;
                Kb[(size_t)(((cc >> 5) * NATOMS) + row) * 32 + (cc & 31)] = f2bf(c);
            } else {
                vt[col - 256][rowin] = f2bf(c);
            }
        }
    }
    __syncthreads();
    if (half == 1 && t < 128) {
        int hh = t >> 5, d = t & 31;
        uint4 a0 = *(const uint4*)&vt[t][0];
        uint4 a1 = *(const uint4*)&vt[t][8];
        ushort* dst = VTb2 + ((size_t)(hh * 64 + (rb >> 6)) * 32 + d) * 64 + (rb & 63);
        *(uint4*)(dst) = a0;
        *(uint4*)(dst + 8) = a1;
    }
}

// ---------------- attention: 32x32x16, S^T/O^T, split-K ----------------------
// z==SPLIT slab (256 light blocks) does k_back weight packs + cell MLP + bidx,
// riding in attn's occupancy slack (consumed only next kernel).
__global__ __launch_bounds__(256) void k_attn(const ushort* __restrict__ Qb,
                                              const ushort* __restrict__ Kb,
                                              const ushort* __restrict__ VTb2,
                                              ushort* __restrict__ Opart,
                                              float* __restrict__ lpart,
                                              const int* __restrict__ num_atoms,
                                              const float* __restrict__ cell,
                                              const float* __restrict__ aow,
                                              const float* __restrict__ op1w,
                                              const float* __restrict__ r1w,
                                              const float* __restrict__ r2w,
                                              const float* __restrict__ ce_w1,
                                              const float* __restrict__ ce_b1,
                                              const float* __restrict__ ce_w2,
                                              const float* __restrict__ ce_b2,
                                              int* __restrict__ bidx,
                                              float* __restrict__ cmin,
                                              float* __restrict__ cmax,
                                              ushort* __restrict__ Wao,
                                              ushort* __restrict__ Wop1,
                                              ushort* __restrict__ Wr1,
                                              ushort* __restrict__ Wr2,
                                              float* __restrict__ CF) {
    __shared__ alignas(16) ushort P_s[4][32 * 72];
    __shared__ alignas(16) float OL[2][32 * 36];
    __shared__ float LL[2][32];
    const int t = threadIdx.x;

    if (blockIdx.z == SPLIT) {
        float* hs = (float*)&P_s[0][0];
        int* start = (int*)&P_s[1][0];
        const int mid = blockIdx.y * 64 + blockIdx.x;   // [0,256)
        for (int j = mid * 256 + t; j < 86016; j += 65536) {
            if (j < 16384) {                     // aow [128][128]
                int k = j >> 7, n = j & 127;
                Wao[n * 128 + k] = f2bf(aow[j]);
            } else if (j < 49536) {              // op1w [259][128]
                int jj = j - 16384; int k = jj >> 7, n = jj & 127;
                Wop1[n * 288 + k] = f2bf(op1w[jj]);
            } else if (j < 53248) {              // zero-pad k in [259,288)
                int jj = j - 49536; int n = jj & 127, k = 259 + (jj >> 7);
                Wop1[n * 288 + k] = 0;
            } else if (j < 69632) {              // r1w [128][128]
                int jj = j - 53248; int k = jj >> 7, n = jj & 127;
                Wr1[n * 128 + k] = f2bf(r1w[jj]);
            } else {                             // r2w [128][128]
                int jj = j - 69632; int k = jj >> 7, n = jj & 127;
                Wr2[n * 128 + k] = f2bf(r2w[jj]);
            }
        }
        if (mid < 128) {
            if (t < 128) {
                float c0 = cell[mid * 3 + 0], c1 = cell[mid * 3 + 1], c2 = cell[mid * 3 + 2];
                float h = c0 * ce_w1[t] + c1 * ce_w1[HD + t] + c2 * ce_w1[2 * HD + t] + ce_b1[t];
                h = h / (1.f + __expf(-h));
                hs[t] = h;
            }
            __syncthreads();
            if (t < 128) {
                float acc = ce_b2[t];
#pragma unroll 8
                for (int k = 0; k < HD; k++) acc += hs[k] * ce_w2[k * HD + t];
                CF[mid * HD + t] = acc;
            }
        } else if (mid == 128) {
            if (t == 0) {
                int pos = 0;
                for (int b = 0; b < BATCH; b++) { start[b] = pos; pos += num_atoms[b]; }
                start[BATCH] = pos;
            }
            __syncthreads();
            if (t < 128) {
                int s = min(start[t], NATOMS), e = min(start[t + 1], NATOMS);
                for (int j = s; j < e; j++) bidx[j] = t;
                if (t == 0) {
                    int total = min(start[BATCH], NATOMS);
                    for (int j = total; j < NATOMS; j++) bidx[j] = BATCH - 1;
                }
            }
            for (int rr = t; rr < BATCH * 3; rr += 256) {
                float a0 = cell[rr * 3 + 0], a1 = cell[rr * 3 + 1], a2 = cell[rr * 3 + 2];
                cmin[rr] = fminf(a0, fminf(a1, a2)) + 1e-6f;
                cmax[rr] = fmaxf(a0, fmaxf(a1, a2)) - 1e-6f;
            }
        }
        return;
    }

    const int w = t >> 6, lane = t & 63;
    const int l31 = lane & 31, hi = lane >> 5;
    const int qt = w & 1, kh2 = w >> 1;
    const int h = blockIdx.y, sp = blockIdx.z;
    const int q0 = blockIdx.x * 64;
    const int qrow = q0 + qt * 32 + l31;

    short8 qf0 = *(const short8*)(Qb + (size_t)(h * NATOMS + qrow) * 32 + hi * 8);
    short8 qf1 = *(const short8*)(Qb + (size_t)(h * NATOMS + qrow) * 32 + 16 + hi * 8);
    f32x16 O = z16();
    float lp = 0.f;
    ushort* Pw = &P_s[w][0];
    const int kstart = sp * (NATOMS / SPLIT) + kh2 * 64;

    for (int ck = 0; ck < (NATOMS / SPLIT) / 128; ck++) {
        int kb = kstart + ck * 128;
        const ushort* vbase = VTb2 + ((size_t)(h * 64 + (kb >> 6)) * 32 + l31) * 64;
#pragma unroll
        for (int kt = 0; kt < 2; kt++) {
            int kk = kb + kt * 32;
            const ushort* kp = Kb + (size_t)(h * NATOMS + kk + l31) * 32 + hi * 8;
            short8 kf0 = *(const short8*)(kp);
            short8 kf1 = *(const short8*)(kp + 16);
            f32x16 S = z16();
            __builtin_amdgcn_s_setprio(1);
            S = __builtin_amdgcn_mfma_f32_32x32x16_bf16(kf0, qf0, S, 0, 0, 0);
            S = __builtin_amdgcn_mfma_f32_32x32x16_bf16(kf1, qf1, S, 0, 0, 0);
            __builtin_amdgcn_s_setprio(0);
#pragma unroll
            for (int c = 0; c < 4; c++) {
                float p0 = exp2f(S[4 * c + 0]);
                float p1 = exp2f(S[4 * c + 1]);
                float p2 = exp2f(S[4 * c + 2]);
                float p3 = exp2f(S[4 * c + 3]);
                lp += (p0 + p1) + (p2 + p3);
                uint2 u;
                asm("v_cvt_pk_bf16_f32 %0, %1, %2" : "=v"(u.x) : "v"(p0), "v"(p1));
                asm("v_cvt_pk_bf16_f32 %0, %1, %2" : "=v"(u.y) : "v"(p2), "v"(p3));
                *(uint2*)(&Pw[l31 * 72 + kt * 32 + c * 8 + hi * 4]) = u;
            }
#pragma unroll
            for (int wd = 0; wd < 2; wd++) {
                int koff = kt * 32 + wd * 16;
                short8 vf = *(const short8*)(vbase + koff + hi * 8);
                short8 pf = *(const short8*)(&Pw[l31 * 72 + koff + hi * 8]);
                __builtin_amdgcn_s_setprio(1);
                O = __builtin_amdgcn_mfma_f32_32x32x16_bf16(vf, pf, O, 0, 0, 0);
                __builtin_amdgcn_s_setprio(0);
            }
        }
    }
    lp += __shfl_xor(lp, 32);
    if (kh2 == 0) {
#pragma unroll
        for (int c = 0; c < 4; c++) {
            float4 f = {O[4 * c + 0], O[4 * c + 1], O[4 * c + 2], O[4 * c + 3]};
            *(float4*)(&OL[qt][l31 * 36 + c * 8 + hi * 4]) = f;
        }
        if (hi == 0) LL[qt][l31] = lp;
    }
    __syncthreads();
    if (kh2 == 1) {
        lp += LL[qt][l31];
#pragma unroll
        for (int c = 0; c < 4; c++) {
            float4 f = *(const float4*)(&OL[qt][l31 * 36 + c * 8 + hi * 4]);
            float o0 = O[4 * c + 0] + f.x, o1 = O[4 * c + 1] + f.y;
            float o2 = O[4 * c + 2] + f.z, o3 = O[4 * c + 3] + f.w;
            uint2 u;
            u.x = (uint32_t)f2bf(o0) | ((uint32_t)f2bf(o1) << 16);
            u.y = (uint32_t)f2bf(o2) | ((uint32_t)f2bf(o3) << 16);
            *(uint2*)(Opart + (size_t)(sp * NATOMS + qrow) * HD + h * 32 + c * 8 + hi * 4) = u;
        }
        if (hi == 0) lpart[sp * (NHEAD * NATOMS) + h * NATOMS + qrow] = lp;
    }
}

// ---------------- back: fused ao+comb+op1+r1+r2+LN+w3+clamp, 8 waves ----------
__global__ __launch_bounds__(512) void k_back(
        const ushort* __restrict__ Opart, const float* __restrict__ lpart,
        const ushort* __restrict__ Wao, const float* __restrict__ aob,
        const float* __restrict__ CF, const float* __restrict__ coord,
        const int* __restrict__ bidx,
        const float* __restrict__ fg, const float* __restrict__ fb,
        const ushort* __restrict__ Wop1, const float* __restrict__ op1b,
        const float* __restrict__ l1g, const float* __restrict__ l1b,
        const ushort* __restrict__ Wr1, const float* __restrict__ r1b,
        const float* __restrict__ rlg, const float* __restrict__ rlb,
        const ushort* __restrict__ Wr2, const float* __restrict__ r2b,
        const float* __restrict__ l2g, const float* __restrict__ l2b,
        const float* __restrict__ w3, const float* __restrict__ b3,
        const float* __restrict__ cmin, const float* __restrict__ cmax,
        float* __restrict__ out) {
    __shared__ alignas(16) ushort AF1[9][64][8];
    __shared__ alignas(16) ushort AF2[4][64][8];
    __shared__ alignas(16) ushort AF3[4][64][8];
    __shared__ float RED[8][16][4];
    __shared__ float REDC[16][2];
    __shared__ float COORDS[16][3];
    const int t = threadIdx.x, w = t >> 6, lane = t & 63, quad = lane >> 4, lq = lane & 15;
    const int rb = blockIdx.x * 16;
    const int col = lq + 16 * w;

    // ---- stage A: split-combine + attn-out GEMM ----
    const int arow = rb + lq;
    float4v a0 = {0.f, 0.f, 0.f, 0.f};
#pragma unroll
    for (int h = 0; h < 4; h++) {
        float l = 0.f;
#pragma unroll
        for (int s = 0; s < SPLIT; s++) l += lpart[s * (NHEAD * NATOMS) + h * NATOMS + arow];
        float inv = 1.f / l;
        float pv[8];
#pragma unroll
        for (int j = 0; j < 8; j++) pv[j] = 0.f;
#pragma unroll
        for (int s = 0; s < SPLIT; s++) {
            short8 ov = *(const short8*)(Opart + (size_t)(s * NATOMS + arow) * HD + h * 32 + quad * 8);
#pragma unroll
            for (int j = 0; j < 8; j++) pv[j] += b2f((ushort)ov[j]);
        }
        short8 af;
#pragma unroll
        for (int j = 0; j < 8; j++) af[j] = (short)f2bf(pv[j] * inv);
        short8 w0 = *(const short8*)(Wao + (size_t)col * HD + h * 32 + quad * 8);
        a0 = __builtin_amdgcn_mfma_f32_16x16x32_bf16(af, w0, a0, 0, 0, 0);
    }
    float x1[4];
#pragma unroll
    for (int r = 0; r < 4; r++) x1[r] = a0[r] + aob[col];

    // ---- stage B: comb LN(259) -> AF1 ----
    float cfv[4];
#pragma unroll
    for (int r = 0; r < 4; r++) cfv[r] = CF[bidx[rb + quad * 4 + r] * HD + col];
#pragma unroll
    for (int r = 0; r < 4; r++) {
        float s1 = x1[r] + cfv[r];
        float s2 = x1[r] * x1[r] + cfv[r] * cfv[r];
#pragma unroll
        for (int m = 1; m < 16; m <<= 1) { s1 += __shfl_xor(s1, m); s2 += __shfl_xor(s2, m); }
        if (lq == 0) { RED[w][quad * 4 + r][0] = s1; RED[w][quad * 4 + r][1] = s2; }
    }
    if (t < 16) {
        float c0 = coord[(rb + t) * 3 + 0], c1 = coord[(rb + t) * 3 + 1], c2 = coord[(rb + t) * 3 + 2];
        COORDS[t][0] = c0; COORDS[t][1] = c1; COORDS[t][2] = c2;
        REDC[t][0] = c0 + c1 + c2; REDC[t][1] = c0 * c0 + c1 * c1 + c2 * c2;
    }
    if (t < 64) { uint4 z = {0, 0, 0, 0}; *(uint4*)&AF1[8][t][0] = z; }
    __syncthreads();
#pragma unroll
    for (int r = 0; r < 4; r++) {
        int ri = quad * 4 + r;
        float s1 = REDC[ri][0], s2 = REDC[ri][1];
#pragma unroll
        for (int ww = 0; ww < 8; ww++) { s1 += RED[ww][ri][0]; s2 += RED[ww][ri][1]; }
        float mn = s1 * (1.f / FDIM);
        float iv = rsqrtf(s2 * (1.f / FDIM) - mn * mn + 1e-5f);
        float vx = (x1[r] - mn) * iv * fg[col] + fb[col];
        float vc = (cfv[r] - mn) * iv * fg[col + 128] + fb[col + 128];
        AF1[col >> 5][((col >> 3) & 3) * 16 + ri][col & 7] = f2bf(vx);
        int c2 = col + 128;
        AF1[c2 >> 5][((c2 >> 3) & 3) * 16 + ri][c2 & 7] = f2bf(vc);
    }
    if (t < 16) {
        float s1 = REDC[t][0], s2 = REDC[t][1];
#pragma unroll
        for (int ww = 0; ww < 8; ww++) { s1 += RED[ww][t][0]; s2 += RED[ww][t][1]; }
        float mn = s1 * (1.f / FDIM);
        float iv = rsqrtf(s2 * (1.f / FDIM) - mn * mn + 1e-5f);
#pragma unroll
        for (int c = 0; c < 3; c++)
            AF1[8][t][c] = f2bf((COORDS[t][c] - mn) * iv * fg[256 + c] + fb[256 + c]);
    }
    __syncthreads();

    // ---- stage C: op1 (K=288) + LN + silu -> AF2 ----
    float4v cv = {0.f, 0.f, 0.f, 0.f};
#pragma unroll
    for (int kt = 0; kt < 9; kt++) {
        short8 af = *(const short8*)&AF1[kt][lane][0];
        short8 w0 = *(const short8*)(Wop1 + (size_t)col * 288 + kt * 32 + quad * 8);
        cv = __builtin_amdgcn_mfma_f32_16x16x32_bf16(af, w0, cv, 0, 0, 0);
    }
    float h0[4];
#pragma unroll
    for (int r = 0; r < 4; r++) {
        h0[r] = cv[r] + op1b[col];
        float s1 = h0[r], s2 = h0[r] * h0[r];
#pragma unroll
        for (int m = 1; m < 16; m <<= 1) { s1 += __shfl_xor(s1, m); s2 += __shfl_xor(s2, m); }
        if (lq == 0) { RED[w][quad * 4 + r][0] = s1; RED[w][quad * 4 + r][1] = s2; }
    }
    __syncthreads();
#pragma unroll
    for (int r = 0; r < 4; r++) {
        int ri = quad * 4 + r;
        float s1 = 0.f, s2 = 0.f;
#pragma unroll
        for (int ww = 0; ww < 8; ww++) { s1 += RED[ww][ri][0]; s2 += RED[ww][ri][1]; }
        float mn = s1 * (1.f / HD);
        float iv = rsqrtf(s2 * (1.f / HD) - mn * mn + 1e-5f);
        float o = (h0[r] - mn) * iv * l1g[col] + l1b[col];
        o = o / (1.f + __expf(-o));
        AF2[col >> 5][((col >> 3) & 3) * 16 + ri][col & 7] = f2bf(o);
    }
    __syncthreads();

    // ---- stage D: r1 + LN + silu -> AF3 ----
    float4v dv = {0.f, 0.f, 0.f, 0.f};
#pragma unroll
    for (int kt = 0; kt < 4; kt++) {
        short8 af = *(const short8*)&AF2[kt][lane][0];
        short8 w0 = *(const short8*)(Wr1 + (size_t)col * HD + kt * 32 + quad * 8);
        dv = __builtin_amdgcn_mfma_f32_16x16x32_bf16(af, w0, dv, 0, 0, 0);
    }
    float e0[4];
#pragma unroll
    for (int r = 0; r < 4; r++) {
        e0[r] = dv[r] + r1b[col];
        float s1 = e0[r], s2 = e0[r] * e0[r];
#pragma unroll
        for (int m = 1; m < 16; m <<= 1) { s1 += __shfl_xor(s1, m); s2 += __shfl_xor(s2, m); }
        if (lq == 0) { RED[w][quad * 4 + r][0] = s1; RED[w][quad * 4 + r][1] = s2; }
    }
    __syncthreads();
#pragma unroll
    for (int r = 0; r < 4; r++) {
        int ri = quad * 4 + r;
        float s1 = 0.f, s2 = 0.f;
#pragma unroll
        for (int ww = 0; ww < 8; ww++) { s1 += RED[ww][ri][0]; s2 += RED[ww][ri][1]; }
        float mn = s1 * (1.f / HD);
        float iv = rsqrtf(s2 * (1.f / HD) - mn * mn + 1e-5f);
        float o = (e0[r] - mn) * iv * rlg[col] + rlb[col];
        o = o / (1.f + __expf(-o));
        AF3[col >> 5][((col >> 3) & 3) * 16 + ri][col & 7] = f2bf(o);
    }
    __syncthreads();

    // ---- stage E: r2 + resid + LN + w3 + tanh + clamp ----
    float4v fv = {0.f, 0.f, 0.f, 0.f};
#pragma unroll
    for (int kt = 0; kt < 4; kt++) {
        short8 af = *(const short8*)&AF3[kt][lane][0];
        short8 w0 = *(const short8*)(Wr2 + (size_t)col * HD + kt * 32 + quad * 8);
        fv = __builtin_amdgcn_mfma_f32_16x16x32_bf16(af, w0, fv, 0, 0, 0);
    }
    float g0r[4];
#pragma unroll
    for (int r = 0; r < 4; r++) {
        int ri = quad * 4 + r;
        float rs = b2f(AF2[col >> 5][((col >> 3) & 3) * 16 + ri][col & 7]);
        g0r[r] = fv[r] + r2b[col] + rs;
        float s1 = g0r[r], s2 = g0r[r] * g0r[r];
#pragma unroll
        for (int m = 1; m < 16; m <<= 1) { s1 += __shfl_xor(s1, m); s2 += __shfl_xor(s2, m); }
        if (lq == 0) { RED[w][ri][0] = s1; RED[w][ri][1] = s2; }
    }
    __syncthreads();
    float tp[4][3];
#pragma unroll
    for (int r = 0; r < 4; r++) {
        int ri = quad * 4 + r;
        float s1 = 0.f, s2 = 0.f;
#pragma unroll
        for (int ww = 0; ww < 8; ww++) { s1 += RED[ww][ri][0]; s2 += RED[ww][ri][1]; }
        float mn = s1 * (1.f / HD);
        float iv = rsqrtf(s2 * (1.f / HD) - mn * mn + 1e-5f);
        float h2 = (g0r[r] - mn) * iv * l2g[col] + l2b[col];
#pragma unroll
        for (int c = 0; c < 3; c++) {
            float v = h2 * w3[col * 3 + c];
#pragma unroll
            for (int m = 1; m < 16; m <<= 1) v += __shfl_xor(v, m);
            tp[r][c] = v;
        }
    }
    __syncthreads();
    if (lq == 0) {
#pragma unroll
        for (int r = 0; r < 4; r++) {
            RED[w][quad * 4 + r][0] = tp[r][0];
            RED[w][quad * 4 + r][1] = tp[r][1];
            RED[w][quad * 4 + r][2] = tp[r][2];
        }
    }
    __syncthreads();
    if (t < 16) {
        int bi = bidx[rb + t];
#pragma unroll
        for (int c = 0; c < 3; c++) {
            float sv = 0.f;
#pragma unroll
            for (int ww = 0; ww < 8; ww++) sv += RED[ww][t][c];
            float off = tanhf(sv + b3[c]) * 0.01f;
            float pert = COORDS[t][c] + off;
            pert = fminf(fmaxf(pert, cmin[bi * 3 + c]), cmax[bi * 3 + c]);
            out[(rb + t) * 3 + c] = pert;
        }
    }
}

extern "C" void kernel_launch(void* const* d_in, const int* in_sizes, int n_in,
                              void* d_out, int out_size, void* d_ws, size_t ws_size,
                              hipStream_t stream) {
    const int* num_atoms = (const int*)d_in[0];
    const int* elems = (const int*)d_in[1];
    const float* cell = (const float*)d_in[2];
    const float* coord = (const float*)d_in[3];
    const float* emb = (const float*)d_in[4];
    const float* ln_in_g = (const float*)d_in[5];
    const float* ln_in_b = (const float*)d_in[6];
    const float* attn_in_w = (const float*)d_in[7];
    const float* attn_in_b = (const float*)d_in[8];
    const float* attn_out_w = (const float*)d_in[9];
    const float* attn_out_b = (const float*)d_in[10];
    const float* ce_w1 = (const float*)d_in[11];
    const float* ce_b1 = (const float*)d_in[12];
    const float* ce_w2 = (const float*)d_in[13];
    const float* ce_b2 = (const float*)d_in[14];
    const float* ln_feat_g = (const float*)d_in[15];
    const float* ln_feat_b = (const float*)d_in[16];
    const float* op_w1 = (const float*)d_in[17];
    const float* op_b1 = (const float*)d_in[18];
    const float* op_ln1_g = (const float*)d_in[19];
    const float* op_ln1_b = (const float*)d_in[20];
    const float* res_w1 = (const float*)d_in[21];
    const float* res_b1 = (const float*)d_in[22];
    const float* res_ln_g = (const float*)d_in[23];
    const float* res_ln_b = (const float*)d_in[24];
    const float* res_w2 = (const float*)d_in[25];
    const float* res_b2 = (const float*)d_in[26];
    const float* op_ln2_g = (const float*)d_in[27];
    const float* op_ln2_b = (const float*)d_in[28];
    const float* op_w3 = (const float*)d_in[29];
    const float* op_b3 = (const float*)d_in[30];

    char* ws = (char*)d_ws;
    const size_t MB = 1u << 20;
    ushort* Qb = (ushort*)(ws);
    ushort* Kb = (ushort*)(ws + 1 * MB);
    ushort* VTb2 = (ushort*)(ws + 2 * MB);
    ushort* Opart = (ushort*)(ws + 3 * MB);
    float* lpart = (float*)(ws + 7 * MB);
    int* bidx = (int*)(ws + 7 * MB + (256u << 10));
    float* cmin = (float*)(ws + 7 * MB + (272u << 10));
    float* cmax = (float*)(ws + 7 * MB + (274u << 10));
    float* CF = (float*)(ws + 7 * MB + (276u << 10));
    ushort* Wao = (ushort*)(ws + 7 * MB + (436u << 10));
    ushort* Wop1 = (ushort*)(ws + 7 * MB + (468u << 10));
    ushort* Wr1 = (ushort*)(ws + 7 * MB + (540u << 10));
    ushort* Wr2 = (ushort*)(ws + 7 * MB + (572u << 10));

    k_qkv<<<512, 256, 0, stream>>>(elems, emb, ln_in_g, ln_in_b, attn_in_w, attn_in_b,
                                   Qb, Kb, VTb2);
    k_attn<<<dim3(NATOMS / 64, NHEAD, SPLIT + 1), 256, 0, stream>>>(
        Qb, Kb, VTb2, Opart, lpart,
        num_atoms, cell, attn_out_w, op_w1, res_w1, res_w2,
        ce_w1, ce_b1, ce_w2, ce_b2, bidx, cmin, cmax,
        Wao, Wop1, Wr1, Wr2, CF);
    k_back<<<256, 512, 0, stream>>>(Opart, lpart, Wao, attn_out_b, CF, coord, bidx,
                                    ln_feat_g, ln_feat_b, Wop1, op_b1, op_ln1_g, op_ln1_b,
                                    Wr1, res_b1, res_ln_g, res_ln_b, Wr2, res_b2,
                                    op_ln2_g, op_ln2_b, op_w3, op_b3, cmin, cmax,
                                    (float*)d_out);
}